// Round 7
// baseline (52.739 us; speedup 1.0000x reference)
//
#include <hip/hip_runtime.h>

typedef __attribute__((ext_vector_type(8))) short short8;
typedef __attribute__((ext_vector_type(4))) float f32x4;
typedef __fp16 h2_t __attribute__((ext_vector_type(2)));

__device__ __forceinline__ unsigned pk_rtz(float a, float b) {
  h2_t h = __builtin_amdgcn_cvt_pkrtz(a, b);
  return __builtin_bit_cast(unsigned, h);
}
__device__ __forceinline__ unsigned pk_rne(float a, float b) {
  unsigned short ha = __builtin_bit_cast(unsigned short, (_Float16)a);
  unsigned short hb = __builtin_bit_cast(unsigned short, (_Float16)b);
  return (unsigned)ha | ((unsigned)hb << 16);
}
__device__ __forceinline__ unsigned short f2bf(float x) {
  unsigned int u = __float_as_uint(x);
  u += 0x7FFFu + ((u >> 16) & 1u);
  return (unsigned short)(u >> 16);
}
__device__ __forceinline__ float bf2f(unsigned short h) {
  return __uint_as_float(((unsigned)h) << 16);
}
__device__ __forceinline__ unsigned pk_bf(float a, float b) {
  unsigned r;
  asm("v_cvt_pk_bf16_f32 %0, %1, %2" : "=v"(r) : "v"(a), "v"(b));
  return r;
}
__device__ __forceinline__ unsigned scale_bf_pair(unsigned w, float s) {
  float f0 = __uint_as_float(w << 16) * s;
  float f1 = __uint_as_float(w & 0xFFFF0000u) * s;
  return pk_bf(f0, f1);
}

__global__ __launch_bounds__(512) void crf_fused_kernel(
    const float* __restrict__ H, const float* __restrict__ W,
    const float* __restrict__ bias,
    const float* __restrict__ startT, const float* __restrict__ endT,
    const float* __restrict__ trans,
    const int* __restrict__ y, const int* __restrict__ y_len,
    float* __restrict__ out)
{
  // union region (131072 B): GEMM staging f16 (56K) / P[128][196] f32 (100K) /
  //                          scan Mbuf 16 x 8KB (128K)
  __shared__ __align__(16) float smem[32768];
  __shared__ __align__(16) unsigned char EAbuf[8192];   // bf16 [64][128B]
  __shared__ __align__(16) unsigned short scbf[128][64]; // exp(s - m_t) bf16
  __shared__ float scm[128];
  __shared__ float emy[128];
  __shared__ __align__(16) float ubuf[64];
  __shared__ float numsh;
  unsigned char* aTh = (unsigned char*)smem;
  unsigned char* aTl = aTh + 16384;
  unsigned char* bTh = aTh + 32768;
  float* P = smem;                              // [128][196]
  unsigned char* Mbase = (unsigned char*)smem;  // scan phase, 128 KB

  const int b    = blockIdx.x;
  const int tid  = threadIdx.x;
  const int lane = tid & 63;
  const int wid  = tid >> 6;
  const int wm   = wid >> 2;
  const int wn   = wid & 3;

  f32x4 acc[4][3] = {};
  const float* Hb = H + (size_t)b * (128 * 512);
  const int len = y_len[b];
  const int* yb = y + b * 128;

  // ---- issue first GEMM tile loads ----
  float4 areg[4], breg[6];
  int aRow[4], aK4[4], bN[6], bK4[6];
  #pragma unroll
  for (int it = 0; it < 4; ++it) { int i = it * 512 + tid; aRow[it] = i >> 4; aK4[it] = i & 15; }
  #pragma unroll
  for (int it = 0; it < 6; ++it) { int i = it * 512 + tid; bN[it] = i >> 4; bK4[it] = i & 15; }
  #pragma unroll
  for (int it = 0; it < 4; ++it)
    areg[it] = ((const float4*)(Hb + aRow[it] * 512))[aK4[it]];
  #pragma unroll
  for (int it = 0; it < 6; ++it)
    breg[it] = ((const float4*)(W + (bN[it] & 63) * 1536 + (bN[it] >> 6) * 512))[bK4[it]];

  // ---- EA build: EA[r][k] = bf16(exp(trans[k][r] - 1)), swizzled ----
  #pragma unroll
  for (int it = 0; it < 2; ++it) {
    int idx = it * 512 + tid;
    int c = idx >> 4, c4 = idx & 15;
    float4 v = ((const float4*)trans)[idx];
    #pragma unroll
    for (int e = 0; e < 4; ++e) {
      int cp = c4 * 4 + e;
      float val = __expf(((const float*)&v)[e] - 1.0f);
      *(unsigned short*)(EAbuf + cp * 128 + ((2 * c) ^ ((cp & 7) << 4))) = f2bf(val);
    }
  }

  // ================= GEMM: f16, A hi/lo split (2 MFMAs) =================
  for (int kk = 0; kk < 512; kk += 64) {
    if (kk) __syncthreads();
    #pragma unroll
    for (int it = 0; it < 4; ++it) {
      float4 v = areg[it];
      h2_t h01 = __builtin_amdgcn_cvt_pkrtz(v.x, v.y);
      h2_t h23 = __builtin_amdgcn_cvt_pkrtz(v.z, v.w);
      float r0 = v.x - (float)h01[0];
      float r1 = v.y - (float)h01[1];
      float r2 = v.z - (float)h23[0];
      float r3 = v.w - (float)h23[1];
      uint2 hi; hi.x = __builtin_bit_cast(unsigned, h01); hi.y = __builtin_bit_cast(unsigned, h23);
      uint2 lo; lo.x = pk_rtz(r0, r1); lo.y = pk_rtz(r2, r3);
      int off = aRow[it] * 128 + ((aK4[it] * 8) ^ ((aRow[it] & 7) << 4));
      *(uint2*)(aTh + off) = hi; *(uint2*)(aTl + off) = lo;
    }
    #pragma unroll
    for (int it = 0; it < 6; ++it) {
      float4 v = breg[it];
      uint2 bh; bh.x = pk_rne(v.x, v.y); bh.y = pk_rne(v.z, v.w);
      int off = bN[it] * 128 + ((bK4[it] * 8) ^ ((bN[it] & 7) << 4));
      *(uint2*)(bTh + off) = bh;
    }
    __syncthreads();
    if (kk < 448) {
      #pragma unroll
      for (int it = 0; it < 4; ++it)
        areg[it] = ((const float4*)(Hb + aRow[it] * 512 + kk + 64))[aK4[it]];
      #pragma unroll
      for (int it = 0; it < 6; ++it)
        breg[it] = ((const float4*)(W + (bN[it] & 63) * 1536 + (bN[it] >> 6) * 512 + kk + 64))[bK4[it]];
    }
    #pragma unroll
    for (int ks = 0; ks < 2; ++ks) {
      const int kbyte = ks * 64 + ((lane >> 4) << 4);
      short8 ah[4], al[4], bh[3];
      #pragma unroll
      for (int m = 0; m < 4; ++m) {
        int row = wm * 64 + m * 16 + (lane & 15);
        int off = row * 128 + (kbyte ^ ((row & 7) << 4));
        ah[m] = *(const short8*)(aTh + off);
        al[m] = *(const short8*)(aTl + off);
      }
      #pragma unroll
      for (int n = 0; n < 3; ++n) {
        int col = wn * 48 + n * 16 + (lane & 15);
        int off = col * 128 + (kbyte ^ ((col & 7) << 4));
        bh[n] = *(const short8*)(bTh + off);
      }
      #pragma unroll
      for (int m = 0; m < 4; ++m)
        #pragma unroll
        for (int n = 0; n < 3; ++n) {
          asm("v_mfma_f32_16x16x32_f16 %0, %1, %2, %0"
              : "+v"(acc[m][n]) : "v"(ah[m]), "v"(bh[n]));
          asm("v_mfma_f32_16x16x32_f16 %0, %1, %2, %0"
              : "+v"(acc[m][n]) : "v"(al[m]), "v"(bh[n]));
        }
    }
  }
  __syncthreads();

  // acc -> P. C/D layout: col = lane&15, row = 4*(lane>>4)+j
  #pragma unroll
  for (int m = 0; m < 4; ++m)
    #pragma unroll
    for (int n = 0; n < 3; ++n) {
      int row0 = wm * 64 + m * 16 + ((lane >> 4) << 2);
      int col  = wn * 48 + n * 16 + (lane & 15);
      #pragma unroll
      for (int j = 0; j < 4; ++j)
        P[(row0 + j) * 196 + col] = acc[m][n][j];
    }
  __syncthreads();

  // fused epilogue: raw score -> row max (scm), emission select (emy),
  //                 exp(s - m_t) packed bf16 -> scbf
  #pragma unroll
  for (int it = 0; it < 4; ++it) {
    int i4 = it * 512 + tid;
    int t = i4 >> 4, c4 = i4 & 15;
    float4 s = *(const float4*)(P + t * 196 + 64 + c4 * 4);
    float4 bb = ((const float4*)bias)[c4];
    s.x += bb.x; s.y += bb.y; s.z += bb.z; s.w += bb.w;
    if (t > 0) {
      float4 g = *(const float4*)(P + (t - 1) * 196 + c4 * 4);
      s.x += g.x; s.y += g.y; s.z += g.z; s.w += g.w;
    }
    if (t < 127) {
      float4 g = *(const float4*)(P + (t + 1) * 196 + 128 + c4 * 4);
      s.x += g.x; s.y += g.y; s.z += g.z; s.w += g.w;
    }
    float m4 = fmaxf(fmaxf(s.x, s.y), fmaxf(s.z, s.w));
    #pragma unroll
    for (int o = 1; o < 16; o <<= 1) m4 = fmaxf(m4, __shfl_xor(m4, o, 64));
    if ((lane & 15) == 0) scm[t] = m4;
    int yt = yb[t];
    if ((yt >> 2) == c4) {
      int r = yt & 3;
      emy[t] = (r == 0) ? s.x : (r == 1) ? s.y : (r == 2) ? s.z : s.w;
    }
    float e0 = __expf(s.x - m4), e1 = __expf(s.y - m4);
    float e2 = __expf(s.z - m4), e3 = __expf(s.w - m4);
    uint2 w2; w2.x = pk_bf(e0, e1); w2.y = pk_bf(e2, e3);
    *(uint2*)&scbf[t][c4 * 4] = w2;
  }
  __syncthreads();

  // ---- numerator on wave 7 (handed to wave 0 via numsh) ----
  if (wid == 7) {
    float p = 0.f;
    #pragma unroll
    for (int rep = 0; rep < 2; ++rep) {
      int t = lane + rep * 64;
      if (t < 127) {
        int yt = yb[t], yt1 = yb[t + 1];
        if (t < len)     p += emy[t];
        if (t + 1 < len) p += trans[yt * 64 + yt1];
      }
    }
    #pragma unroll
    for (int s = 32; s > 0; s >>= 1) p += __shfl_xor(p, s, 64);
    float nm = p + startT[yb[0]] + endT[yb[len - 1]];
    if (len == 128) nm += emy[127];
    if (lane == 0) numsh = nm;
  }

  // ---- chunk phase: wave w builds chunks w and w+8 (8 steps each) ----
  {
    short8 ea[4][2];
    #pragma unroll
    for (int rt = 0; rt < 4; ++rt)
      #pragma unroll
      for (int kh = 0; kh < 2; ++kh) {
        int row = rt * 16 + (lane & 15);
        int kb = kh * 64 + ((lane >> 4) << 4);
        ea[rt][kh] = *(const short8*)(EAbuf + row * 128 + (kb ^ ((row & 7) << 4)));
      }
    f32x4 z4 = {0.f, 0.f, 0.f, 0.f};

    const int cA = wid, cB = wid + 8;
    unsigned char* MbA = Mbase + cA * 8192;
    unsigned char* MbB = Mbase + cB * 8192;
    const int t0A = (cA == 0) ? 1 : 8 * cA;
    const int t1A = (8 * cA + 7 < len - 1) ? 8 * cA + 7 : len - 1;
    const int t0B = 8 * cB;
    const int t1B = (8 * cB + 7 < len - 1) ? 8 * cB + 7 : len - 1;
    const int sw2 = (lane & 7) << 4;

    if (t0A <= t1A) {
      float s0 = bf2f(scbf[t0A][lane]);
      #pragma unroll
      for (int j = 0; j < 8; ++j) {
        uint4 w = *(const uint4*)(EAbuf + lane * 128 + ((j * 16) ^ sw2));
        uint4 o;
        o.x = scale_bf_pair(w.x, s0); o.y = scale_bf_pair(w.y, s0);
        o.z = scale_bf_pair(w.z, s0); o.w = scale_bf_pair(w.w, s0);
        *(uint4*)(MbA + lane * 128 + ((j * 16) ^ sw2)) = o;
      }
    }
    if (t0B <= t1B) {
      float s0 = bf2f(scbf[t0B][lane]);
      #pragma unroll
      for (int j = 0; j < 8; ++j) {
        uint4 w = *(const uint4*)(EAbuf + lane * 128 + ((j * 16) ^ sw2));
        uint4 o;
        o.x = scale_bf_pair(w.x, s0); o.y = scale_bf_pair(w.y, s0);
        o.z = scale_bf_pair(w.z, s0); o.w = scale_bf_pair(w.w, s0);
        *(uint4*)(MbB + lane * 128 + ((j * 16) ^ sw2)) = o;
      }
    }

    #pragma unroll 1
    for (int i = 1; i <= 7; ++i) {
      int tA = t0A + i, tB = t0B + i;
      bool dA = (tA <= t1A), dB = (tB <= t1B);
      // issue reads for BOTH chains first
      short8 mfA[4][2], mfB[4][2];
      #pragma unroll
      for (int ct = 0; ct < 4; ++ct)
        #pragma unroll
        for (int kh = 0; kh < 2; ++kh) {
          int row = ct * 16 + (lane & 15);
          int kb = kh * 64 + ((lane >> 4) << 4);
          int off = row * 128 + (kb ^ ((row & 7) << 4));
          mfA[ct][kh] = *(const short8*)(MbA + off);
          mfB[ct][kh] = *(const short8*)(MbB + off);
        }
      f32x4 svA[4], svB[4];
      #pragma unroll
      for (int rt = 0; rt < 4; ++rt) {
        int cidx = rt * 16 + ((lane >> 4) << 2);
        ushort4 ra = *(const ushort4*)&scbf[tA][cidx];
        ushort4 rb = *(const ushort4*)&scbf[tB][cidx];
        svA[rt][0] = bf2f(ra.x); svA[rt][1] = bf2f(ra.y);
        svA[rt][2] = bf2f(ra.z); svA[rt][3] = bf2f(ra.w);
        svB[rt][0] = bf2f(rb.x); svB[rt][1] = bf2f(rb.y);
        svB[rt][2] = bf2f(rb.z); svB[rt][3] = bf2f(rb.w);
      }
      // chain A
      {
        f32x4 c[4][4];
        #pragma unroll
        for (int rt = 0; rt < 4; ++rt)
          #pragma unroll
          for (int ct = 0; ct < 4; ++ct) {
            asm("v_mfma_f32_16x16x32_bf16 %0, %1, %2, %3"
                : "=&v"(c[rt][ct]) : "v"(ea[rt][0]), "v"(mfA[ct][0]), "v"(z4));
            asm("v_mfma_f32_16x16x32_bf16 %0, %1, %2, %0"
                : "+v"(c[rt][ct]) : "v"(ea[rt][1]), "v"(mfA[ct][1]));
          }
        if (dA) {
          #pragma unroll
          for (int rt = 0; rt < 4; ++rt)
            #pragma unroll
            for (int ct = 0; ct < 4; ++ct) {
              f32x4 cc = c[rt][ct] * svA[rt];
              uint2 w2; w2.x = pk_bf(cc[0], cc[1]); w2.y = pk_bf(cc[2], cc[3]);
              int row = ct * 16 + (lane & 15);
              int byt = 2 * (rt * 16 + ((lane >> 4) << 2));
              *(uint2*)(MbA + row * 128 + (byt ^ ((row & 7) << 4))) = w2;
            }
        }
      }
      // chain B
      {
        f32x4 c[4][4];
        #pragma unroll
        for (int rt = 0; rt < 4; ++rt)
          #pragma unroll
          for (int ct = 0; ct < 4; ++ct) {
            asm("v_mfma_f32_16x16x32_bf16 %0, %1, %2, %3"
                : "=&v"(c[rt][ct]) : "v"(ea[rt][0]), "v"(mfB[ct][0]), "v"(z4));
            asm("v_mfma_f32_16x16x32_bf16 %0, %1, %2, %0"
                : "+v"(c[rt][ct]) : "v"(ea[rt][1]), "v"(mfB[ct][1]));
          }
        if (dB) {
          #pragma unroll
          for (int rt = 0; rt < 4; ++rt)
            #pragma unroll
            for (int ct = 0; ct < 4; ++ct) {
              f32x4 cc = c[rt][ct] * svB[rt];
              uint2 w2; w2.x = pk_bf(cc[0], cc[1]); w2.y = pk_bf(cc[2], cc[3]);
              int row = ct * 16 + (lane & 15);
              int byt = 2 * (rt * 16 + ((lane >> 4) << 2));
              *(uint2*)(MbB + row * 128 + (byt ^ ((row & 7) << 4))) = w2;
            }
        }
      }
    }
  }
  __syncthreads();
  if (wid != 0) return;

  // ---- wave 0: combine u <- u * B_k over 16 chunks, then logZ ----
  float eE = __expf(endT[lane]);
  float ls;
  {
    int t1 = 1 + lane, t2 = 65 + lane;
    float a = (t1 <= len - 1) ? (scm[t1] + 1.0f) : 0.f;
    if (t2 <= len - 1) a += scm[t2] + 1.0f;
    #pragma unroll
    for (int s = 32; s > 0; s >>= 1) a += __shfl_xor(a, s, 64);
    ls = a + scm[0];
  }
  float u = __expf(startT[lane]) * bf2f(scbf[0][lane]);

  for (int k = 0; k < 16; ++k) {
    if (k && 8 * k >= len) break;
    int lo = (k == 0) ? 1 : 8 * k;
    int hi = 8 * k + 7; if (hi > len - 1) hi = len - 1;
    if (lo > hi) continue;
    float r = u;
    #pragma unroll
    for (int s = 32; s > 0; s >>= 1) r = fmaxf(r, __shfl_xor(r, s, 64));
    unsigned br = __float_as_uint(r) & 0x7F800000u;
    u *= __uint_as_float(0x7F000000u - br);
    ls += (float)((int)(br >> 23) - 127) * 0.69314718055994531f;
    const unsigned char* Mb = Mbase + k * 8192;
    ubuf[lane] = u;
    float v0 = 0.f, v1 = 0.f, v2 = 0.f, v3 = 0.f;
    #pragma unroll 4
    for (int c = 0; c < 64; c += 4) {
      float4 uu = *(const float4*)&ubuf[c];
      float m0 = bf2f(*(const unsigned short*)(Mb + (c + 0) * 128 + ((2 * lane) ^ (((c + 0) & 7) << 4))));
      float m1 = bf2f(*(const unsigned short*)(Mb + (c + 1) * 128 + ((2 * lane) ^ (((c + 1) & 7) << 4))));
      float m2 = bf2f(*(const unsigned short*)(Mb + (c + 2) * 128 + ((2 * lane) ^ (((c + 2) & 7) << 4))));
      float m3 = bf2f(*(const unsigned short*)(Mb + (c + 3) * 128 + ((2 * lane) ^ (((c + 3) & 7) << 4))));
      v0 = fmaf(uu.x, m0, v0);
      v1 = fmaf(uu.y, m1, v1);
      v2 = fmaf(uu.z, m2, v2);
      v3 = fmaf(uu.w, m3, v3);
    }
    u = (v0 + v1) + (v2 + v3);
  }

  float x = u * eE;
  #pragma unroll
  for (int s = 32; s > 0; s >>= 1) x += __shfl_xor(x, s, 64);
  if (lane == 0) out[b] = numsh - (__logf(x) + ls);
}

extern "C" void kernel_launch(void* const* d_in, const int* in_sizes, int n_in,
                              void* d_out, int out_size, void* d_ws, size_t ws_size,
                              hipStream_t stream) {
  const float* H      = (const float*)d_in[0];
  const float* W      = (const float*)d_in[1];
  const float* bias   = (const float*)d_in[2];
  const float* startT = (const float*)d_in[3];
  const float* endT   = (const float*)d_in[4];
  const float* trans  = (const float*)d_in[5];
  const int*   y      = (const int*)d_in[6];
  const int*   y_len  = (const int*)d_in[8];
  float* out = (float*)d_out;

  crf_fused_kernel<<<dim3(256), dim3(512), 0, stream>>>(
      H, W, bias, startT, endT, trans, y, y_len, out);
}

// Round 9
// 43.752 us; speedup vs baseline: 1.2054x; 1.2054x over previous
//
#include <hip/hip_runtime.h>

typedef __attribute__((ext_vector_type(8))) short short8;
typedef __attribute__((ext_vector_type(4))) float f32x4;

__device__ __forceinline__ unsigned pk_rne(float a, float b) {
  unsigned short ha = __builtin_bit_cast(unsigned short, (_Float16)a);
  unsigned short hb = __builtin_bit_cast(unsigned short, (_Float16)b);
  return (unsigned)ha | ((unsigned)hb << 16);
}
__device__ __forceinline__ unsigned short f2bf(float x) {
  unsigned int u = __float_as_uint(x);
  u += 0x7FFFu + ((u >> 16) & 1u);
  return (unsigned short)(u >> 16);
}
__device__ __forceinline__ float bf2f(unsigned short h) {
  return __uint_as_float(((unsigned)h) << 16);
}
__device__ __forceinline__ unsigned pk_bf(float a, float b) {
  unsigned r;
  asm("v_cvt_pk_bf16_f32 %0, %1, %2" : "=v"(r) : "v"(a), "v"(b));
  return r;
}
__device__ __forceinline__ unsigned scale_bf_pair(unsigned w, float s) {
  float f0 = __uint_as_float(w << 16) * s;
  float f1 = __uint_as_float(w & 0xFFFF0000u) * s;
  return pk_bf(f0, f1);
}

__global__ __launch_bounds__(512) void crf_fused_kernel(
    const float* __restrict__ H, const float* __restrict__ W,
    const float* __restrict__ bias,
    const float* __restrict__ startT, const float* __restrict__ endT,
    const float* __restrict__ trans,
    const int* __restrict__ y, const int* __restrict__ y_len,
    float* __restrict__ out)
{
  // union region: GEMM staging f16 (aTh 16K | bTh 24K = 40K) /
  //               P[128][196] f32 (100K) / scan Mbuf 8 x 8KB (64K)
  __shared__ __align__(16) float smem[25088];
  __shared__ __align__(16) unsigned char EAbuf[8192];  // bf16 [64][128B]
  __shared__ __align__(16) float sc[128][68];          // raw scores then exp
  __shared__ float scm[128];
  __shared__ float emy[128];
  __shared__ __align__(16) float ubuf[64];
  unsigned char* aTh = (unsigned char*)smem;
  unsigned char* bTh = aTh + 16384;
  float* P = smem;                              // [128][196]
  unsigned char* Mbase = (unsigned char*)smem;  // scan phase, 8 x 8KB

  const int b    = blockIdx.x;
  const int tid  = threadIdx.x;
  const int lane = tid & 63;
  const int wid  = tid >> 6;
  const int wm   = wid >> 2;
  const int wn   = wid & 3;

  f32x4 acc[4][3] = {};
  const float* Hb = H + (size_t)b * (128 * 512);
  const int len = y_len[b];
  const int* yb = y + b * 128;

  // ---- issue first GEMM tile loads ----
  float4 areg[4], breg[6];
  int aRow[4], aK4[4], bN[6], bK4[6];
  #pragma unroll
  for (int it = 0; it < 4; ++it) { int i = it * 512 + tid; aRow[it] = i >> 4; aK4[it] = i & 15; }
  #pragma unroll
  for (int it = 0; it < 6; ++it) { int i = it * 512 + tid; bN[it] = i >> 4; bK4[it] = i & 15; }
  #pragma unroll
  for (int it = 0; it < 4; ++it)
    areg[it] = ((const float4*)(Hb + aRow[it] * 512))[aK4[it]];
  #pragma unroll
  for (int it = 0; it < 6; ++it)
    breg[it] = ((const float4*)(W + (bN[it] & 63) * 1536 + (bN[it] >> 6) * 512))[bK4[it]];

  // ---- EA build: EA[r][k] = bf16(exp(trans[k][r] - 1)), swizzled ----
  #pragma unroll
  for (int it = 0; it < 2; ++it) {
    int idx = it * 512 + tid;
    int c = idx >> 4, c4 = idx & 15;
    float4 v = ((const float4*)trans)[idx];
    #pragma unroll
    for (int e = 0; e < 4; ++e) {
      int cp = c4 * 4 + e;
      float val = __expf(((const float*)&v)[e] - 1.0f);
      *(unsigned short*)(EAbuf + cp * 128 + ((2 * c) ^ ((cp & 7) << 4))) = f2bf(val);
    }
  }

  // ================= GEMM: single f16 RNE, 1 MFMA per (m,n) =================
  for (int kk = 0; kk < 512; kk += 64) {
    if (kk) __syncthreads();
    #pragma unroll
    for (int it = 0; it < 4; ++it) {
      float4 v = areg[it];
      uint2 hi; hi.x = pk_rne(v.x, v.y); hi.y = pk_rne(v.z, v.w);
      int off = aRow[it] * 128 + ((aK4[it] * 8) ^ ((aRow[it] & 7) << 4));
      *(uint2*)(aTh + off) = hi;
    }
    #pragma unroll
    for (int it = 0; it < 6; ++it) {
      float4 v = breg[it];
      uint2 bh; bh.x = pk_rne(v.x, v.y); bh.y = pk_rne(v.z, v.w);
      int off = bN[it] * 128 + ((bK4[it] * 8) ^ ((bN[it] & 7) << 4));
      *(uint2*)(bTh + off) = bh;
    }
    __syncthreads();
    if (kk < 448) {
      #pragma unroll
      for (int it = 0; it < 4; ++it)
        areg[it] = ((const float4*)(Hb + aRow[it] * 512 + kk + 64))[aK4[it]];
      #pragma unroll
      for (int it = 0; it < 6; ++it)
        breg[it] = ((const float4*)(W + (bN[it] & 63) * 1536 + (bN[it] >> 6) * 512 + kk + 64))[bK4[it]];
    }
    #pragma unroll
    for (int ks = 0; ks < 2; ++ks) {
      const int kbyte = ks * 64 + ((lane >> 4) << 4);
      short8 ah[4], bh[3];
      #pragma unroll
      for (int m = 0; m < 4; ++m) {
        int row = wm * 64 + m * 16 + (lane & 15);
        ah[m] = *(const short8*)(aTh + row * 128 + (kbyte ^ ((row & 7) << 4)));
      }
      #pragma unroll
      for (int n = 0; n < 3; ++n) {
        int col = wn * 48 + n * 16 + (lane & 15);
        bh[n] = *(const short8*)(bTh + col * 128 + (kbyte ^ ((col & 7) << 4)));
      }
      #pragma unroll
      for (int m = 0; m < 4; ++m)
        #pragma unroll
        for (int n = 0; n < 3; ++n)
          asm("v_mfma_f32_16x16x32_f16 %0, %1, %2, %0"
              : "+v"(acc[m][n]) : "v"(ah[m]), "v"(bh[n]));
    }
  }
  __syncthreads();

  // acc -> P. C/D layout: col = lane&15, row = 4*(lane>>4)+j
  #pragma unroll
  for (int m = 0; m < 4; ++m)
    #pragma unroll
    for (int n = 0; n < 3; ++n) {
      int row0 = wm * 64 + m * 16 + ((lane >> 4) << 2);
      int col  = wn * 48 + n * 16 + (lane & 15);
      #pragma unroll
      for (int j = 0; j < 4; ++j)
        P[(row0 + j) * 196 + col] = acc[m][n][j];
    }
  __syncthreads();

  // epilogue: P -> sc (raw), fused row-max -> scm, emission select -> emy
  #pragma unroll
  for (int it = 0; it < 4; ++it) {
    int i4 = it * 512 + tid;
    int t = i4 >> 4, c4 = i4 & 15;
    float4 s = *(const float4*)(P + t * 196 + 64 + c4 * 4);
    float4 bb = ((const float4*)bias)[c4];
    s.x += bb.x; s.y += bb.y; s.z += bb.z; s.w += bb.w;
    if (t > 0) {
      float4 g = *(const float4*)(P + (t - 1) * 196 + c4 * 4);
      s.x += g.x; s.y += g.y; s.z += g.z; s.w += g.w;
    }
    if (t < 127) {
      float4 g = *(const float4*)(P + (t + 1) * 196 + 128 + c4 * 4);
      s.x += g.x; s.y += g.y; s.z += g.z; s.w += g.w;
    }
    *(float4*)(&sc[t][c4 * 4]) = s;
    float m4 = fmaxf(fmaxf(s.x, s.y), fmaxf(s.z, s.w));
    #pragma unroll
    for (int o = 1; o < 16; o <<= 1) m4 = fmaxf(m4, __shfl_xor(m4, o, 64));
    if ((lane & 15) == 0) scm[t] = m4;
    int yt = yb[t];
    if ((yt >> 2) == c4) {
      int r = yt & 3;
      emy[t] = (r == 0) ? s.x : (r == 1) ? s.y : (r == 2) ? s.z : s.w;
    }
  }
  __syncthreads();

  // transform sc -> exp(sc - m_t) (all waves); numerator on wave 0
  {
    int row = tid >> 2, c0 = (tid & 3) << 4;
    float mt = scm[row];
    float4* p4 = (float4*)&sc[row][c0];
    #pragma unroll
    for (int j = 0; j < 4; ++j) {
      float4 x = p4[j];
      x.x = __expf(x.x - mt); x.y = __expf(x.y - mt);
      x.z = __expf(x.z - mt); x.w = __expf(x.w - mt);
      p4[j] = x;
    }
  }
  float num = 0.f;
  if (wid == 0) {
    float p = 0.f;
    #pragma unroll
    for (int rep = 0; rep < 2; ++rep) {
      int t = lane + rep * 64;
      if (t < 127) {
        int yt = yb[t], yt1 = yb[t + 1];
        if (t < len)     p += emy[t];
        if (t + 1 < len) p += trans[yt * 64 + yt1];
      }
    }
    #pragma unroll
    for (int s = 32; s > 0; s >>= 1) p += __shfl_xor(p, s, 64);
    num = p + startT[yb[0]] + endT[yb[len - 1]];
    if (len == 128) num += emy[127];
  }
  __syncthreads();

  // ---- chunk phase: wave w builds B_w = prod A_t, t in [t0, t1] ----
  {
    unsigned char* Mb = Mbase + wid * 8192;
    int t0 = (wid == 0) ? 1 : 16 * wid;
    int t1 = 16 * wid + 15; if (t1 > len - 1) t1 = len - 1;
    if (t0 <= t1) {
      const int sw = (lane & 7) << 4;
      float s0 = sc[t0][lane];
      #pragma unroll
      for (int j = 0; j < 8; ++j) {
        uint4 w = *(const uint4*)(EAbuf + lane * 128 + ((j * 16) ^ sw));
        uint4 o;
        o.x = scale_bf_pair(w.x, s0); o.y = scale_bf_pair(w.y, s0);
        o.z = scale_bf_pair(w.z, s0); o.w = scale_bf_pair(w.w, s0);
        *(uint4*)(Mb + lane * 128 + ((j * 16) ^ sw)) = o;
      }
      short8 ea[4][2];
      #pragma unroll
      for (int rt = 0; rt < 4; ++rt)
        #pragma unroll
        for (int kh = 0; kh < 2; ++kh) {
          int row = rt * 16 + (lane & 15);
          int kb = kh * 64 + ((lane >> 4) << 4);
          ea[rt][kh] = *(const short8*)(EAbuf + row * 128 + (kb ^ ((row & 7) << 4)));
        }
      f32x4 z4 = {0.f, 0.f, 0.f, 0.f};
      for (int t = t0 + 1; t <= t1; ++t) {
        short8 mf[4][2];
        #pragma unroll
        for (int ct = 0; ct < 4; ++ct)
          #pragma unroll
          for (int kh = 0; kh < 2; ++kh) {
            int row = ct * 16 + (lane & 15);
            int kb = kh * 64 + ((lane >> 4) << 4);
            mf[ct][kh] = *(const short8*)(Mb + row * 128 + (kb ^ ((row & 7) << 4)));
          }
        f32x4 sv[4];
        #pragma unroll
        for (int rt = 0; rt < 4; ++rt)
          sv[rt] = *(const f32x4*)(&sc[t][rt * 16 + ((lane >> 4) << 2)]);
        f32x4 c[4][4];
        #pragma unroll
        for (int rt = 0; rt < 4; ++rt)
          #pragma unroll
          for (int ct = 0; ct < 4; ++ct) {
            asm("v_mfma_f32_16x16x32_bf16 %0, %1, %2, %3"
                : "=&v"(c[rt][ct]) : "v"(ea[rt][0]), "v"(mf[ct][0]), "v"(z4));
            asm("v_mfma_f32_16x16x32_bf16 %0, %1, %2, %0"
                : "+v"(c[rt][ct]) : "v"(ea[rt][1]), "v"(mf[ct][1]));
          }
        #pragma unroll
        for (int rt = 0; rt < 4; ++rt)
          #pragma unroll
          for (int ct = 0; ct < 4; ++ct) {
            f32x4 cc = c[rt][ct] * sv[rt];
            uint2 w2; w2.x = pk_bf(cc[0], cc[1]); w2.y = pk_bf(cc[2], cc[3]);
            int row = ct * 16 + (lane & 15);
            int byt = 2 * (rt * 16 + ((lane >> 4) << 2));
            *(uint2*)(Mb + row * 128 + (byt ^ ((row & 7) << 4))) = w2;
          }
      }
    }
  }
  __syncthreads();
  if (wid != 0) return;

  // ---- wave 0: combine u^T B_0 ... B_7, then logZ ----
  float eE = __expf(endT[lane]);
  float ls;
  {
    int t1 = 1 + lane, t2 = 65 + lane;
    float a = (t1 <= len - 1) ? (scm[t1] + 1.0f) : 0.f;
    if (t2 <= len - 1) a += scm[t2] + 1.0f;
    #pragma unroll
    for (int s = 32; s > 0; s >>= 1) a += __shfl_xor(a, s, 64);
    ls = a + scm[0];
  }
  float u = __expf(startT[lane]) * sc[0][lane];

  for (int k = 0; k < 8; ++k) {
    if (k && 16 * k >= len) break;
    int lo = (k == 0) ? 1 : 16 * k;
    int hi = 16 * k + 15; if (hi > len - 1) hi = len - 1;
    if (lo > hi) continue;
    float r = u;
    #pragma unroll
    for (int s = 32; s > 0; s >>= 1) r = fmaxf(r, __shfl_xor(r, s, 64));
    unsigned br = __float_as_uint(r) & 0x7F800000u;
    u *= __uint_as_float(0x7F000000u - br);
    ls += (float)((int)(br >> 23) - 127) * 0.69314718055994531f;
    const unsigned char* Mb = Mbase + k * 8192;
    ubuf[lane] = u;
    float v0 = 0.f, v1 = 0.f, v2 = 0.f, v3 = 0.f;
    #pragma unroll 4
    for (int c = 0; c < 64; c += 4) {
      float4 uu = *(const float4*)&ubuf[c];
      float m0 = bf2f(*(const unsigned short*)(Mb + (c + 0) * 128 + ((2 * lane) ^ (((c + 0) & 7) << 4))));
      float m1 = bf2f(*(const unsigned short*)(Mb + (c + 1) * 128 + ((2 * lane) ^ (((c + 1) & 7) << 4))));
      float m2 = bf2f(*(const unsigned short*)(Mb + (c + 2) * 128 + ((2 * lane) ^ (((c + 2) & 7) << 4))));
      float m3 = bf2f(*(const unsigned short*)(Mb + (c + 3) * 128 + ((2 * lane) ^ (((c + 3) & 7) << 4))));
      v0 = fmaf(uu.x, m0, v0);
      v1 = fmaf(uu.y, m1, v1);
      v2 = fmaf(uu.z, m2, v2);
      v3 = fmaf(uu.w, m3, v3);
    }
    u = (v0 + v1) + (v2 + v3);
  }

  float x = u * eE;
  #pragma unroll
  for (int s = 32; s > 0; s >>= 1) x += __shfl_xor(x, s, 64);
  if (lane == 0) out[b] = num - (__logf(x) + ls);
}

extern "C" void kernel_launch(void* const* d_in, const int* in_sizes, int n_in,
                              void* d_out, int out_size, void* d_ws, size_t ws_size,
                              hipStream_t stream) {
  const float* H      = (const float*)d_in[0];
  const float* W      = (const float*)d_in[1];
  const float* bias   = (const float*)d_in[2];
  const float* startT = (const float*)d_in[3];
  const float* endT   = (const float*)d_in[4];
  const float* trans  = (const float*)d_in[5];
  const int*   y      = (const int*)d_in[6];
  const int*   y_len  = (const int*)d_in[8];
  float* out = (float*)d_out;

  crf_fused_kernel<<<dim3(256), dim3(512), 0, stream>>>(
      H, W, bias, startT, endT, trans, y, y_len, out);
}